// Round 3
// baseline (224.746 us; speedup 1.0000x reference)
//
#include <hip/hip_runtime.h>
#include <stdint.h>

// DBSCAN-on-voxel-grid, exact port of the JAX reference for batch_size==1.
// Grid 512x512, eps=1.5 => 8-connected adjacency, min_samples=5 (voxels,
// incl. self), clusters with <20 voxels dropped.
//
// R9 = single fused kernel, 256 blocks, with a *cache-maintenance-free*
// device barrier. Key idea: every cross-block-shared datum is accessed only
// via device-coherent ops (atomic RMWs, or __hip_atomic relaxed/agent
// load+store = sc1, which bypass the non-coherent per-XCD L2), OR is
// immutable-after-write and first plain-read only after the barrier that
// follows its last write (kernel start invalidates caches, so no stale L2
// copy can exist). Hence the barrier needs NO buffer_wbl2/buffer_inv:
// __syncthreads() already drains each wave's vmem (waitcnt vmcnt(0) before
// s_barrier), then a relaxed fetch_add + relaxed spin suffices.
// Coherence audit per array:
//   occ : atomicOr writes (PA), plain reads from PB on (immutable after PA)
//   pre : sc1 stores (PB block0), plain reads from PC on (immutable)
//   cm  : sc1 stores (PB), plain reads from PC on (immutable)
//   lab : NEVER plain-accessed: sc1 init (PA), atomicCAS/sc1-loads (PC/PD),
//         sc1 final stores (PD), sc1 reads (PF)
//   cnt : sc1 zero (PA), atomicAdd (PD), sc1 reads (PE)
//   rootbm: sc1 zero (PA), atomicOr (PD), sc1 reads (PE)
//   keep/rpre/rootbm-copy: LDS-local (PE computed redundantly per block)
// Also: word-level bit iteration in PC/PD (97% of the 262K cells are empty),
// and per-block PE removes the PE->PF barrier => 4 barriers total.

#define GRIDW 512
#define WPR 16        // bitmap words per row
#define NWORDS 8192   // 512*512/32
#define NONE 0xFFFFFFFFu
#define NB 256        // blocks; <= CU count, 1 block/CU => co-resident

// ---- ws layout (uint32 units) ----
#define OFF_OCC    0       // 8192: occupancy bitmap        (memset)
#define OFF_BAR    8192    // 128: barrier counters, 16-word spaced (memset)
#define OFF_CNT    8320    // 8192: per-root voxel counts   (sc1-zeroed in PA)
#define OFF_ROOTBM 16512   // 256                            (sc1-zeroed in PA)
#define OFF_CM     17024   // 8192: core mask per word
#define OFF_LAB    25216   // 8192: union-find / final labels (by rank)
#define OFF_PRE    33408   // 8192: exclusive voxel-rank prefix per word
#define MEMSET_BYTES ((8192 + 128) * 4)

#define AL(p) __hip_atomic_load((p), __ATOMIC_RELAXED, __HIP_MEMORY_SCOPE_AGENT)
#define AS(p, v) __hip_atomic_store((p), (v), __ATOMIC_RELAXED, __HIP_MEMORY_SCOPE_AGENT)

// device-wide arrival barrier, no release/acquire cache ops needed (see
// coherence audit above). __syncthreads() drains each wave's vmem before
// s_barrier, so all this block's sc1 stores / atomics are at the coherence
// point before tid0 announces arrival.
__device__ __forceinline__ void gsync(uint32_t* ws, int idx) {
  __syncthreads();
  if (threadIdx.x == 0) {
    uint32_t* c = ws + OFF_BAR + idx * 16;
    __hip_atomic_fetch_add(c, 1u, __ATOMIC_RELAXED, __HIP_MEMORY_SCOPE_AGENT);
    while (AL(c) < (uint32_t)NB) __builtin_amdgcn_s_sleep(2);
    asm volatile("" ::: "memory");
  }
  __syncthreads();
}

// per-position horizontal (west+self+east) 2-bit counts for a row of 32 cells
__device__ __forceinline__ void hsum(uint32_t l, uint32_t c, uint32_t r,
                                     uint32_t& h0, uint32_t& h1) {
  uint32_t Wb = (c << 1) | (l >> 31);
  uint32_t Eb = (c >> 1) | (r << 31);
  h0 = Wb ^ c ^ Eb;
  h1 = (Wb & c) | (Eb & (Wb ^ c));
}

// per-position (sum of three 2-bit row counts) >= 5 (bit-sliced adders)
__device__ __forceinline__ uint32_t ge5(uint32_t a0, uint32_t a1, uint32_t b0,
                                        uint32_t b1, uint32_t c0, uint32_t c1) {
  uint32_t u0 = a0 ^ b0, cy = a0 & b0;
  uint32_t t = a1 ^ b1;
  uint32_t u1 = t ^ cy;
  uint32_t u2 = (a1 & b1) | (cy & t);
  uint32_t v0 = u0 ^ c0, k0 = u0 & c0;
  uint32_t t2 = u1 ^ c1;
  uint32_t v1 = t2 ^ k0;
  uint32_t k1 = (u1 & c1) | (k0 & t2);
  uint32_t v2 = u2 ^ k1;
  uint32_t v3 = u2 & k1;
  return v3 | (v2 & (v1 | v0));  // count in {5..9}
}

// find root with guarded path compression: links are only ever LOWERED
// (write r into L[x] only while r < current link), preserving the
// monotone-decreasing invariant => no cycles, guaranteed termination.
__device__ __forceinline__ uint32_t findc(uint32_t* L, uint32_t x) {
  uint32_t r = x, p = AL(&L[r]);
  while (p != r) { r = p; p = AL(&L[r]); }
  while (x > r) {
    uint32_t nx = AL(&L[x]);
    if (nx <= r) break;          // someone already lowered it at least as far
    atomicCAS(&L[x], nx, r);     // best effort, only writes a smaller value
    x = nx;
  }
  return r;
}

// link larger root under smaller => final root == min core rank of component
__device__ __forceinline__ void unite(uint32_t* L, uint32_t a, uint32_t b) {
  for (;;) {
    a = findc(L, a);
    b = findc(L, b);
    if (a == b) return;
    uint32_t lo = min(a, b), hi = max(a, b);
    if (atomicCAS(&L[hi], hi, lo) == hi) return;  // hi still root => linked
    a = lo; b = hi;
  }
}

__global__ __launch_bounds__(256, 1) void k_all(const float* __restrict__ pts,
                                                uint32_t* __restrict__ ws,
                                                float* __restrict__ out,
                                                int npts) {
  const int tid = threadIdx.x;
  const int gtid = blockIdx.x * 256 + tid;
  const int T = NB * 256;
  __shared__ uint32_t wsum[4];
  __shared__ uint32_t s_rootbm[256];
  __shared__ uint32_t s_keep[256];
  __shared__ uint32_t s_rpre[256];
  __shared__ int smax;

  // ---- PA: sc1-init cnt/lab/rootbm; voxelize points (occ pre-zeroed by
  //          memset; zeroing and atomicOr touch disjoint arrays) ----
  for (int i = gtid; i < NWORDS; i += T) {
    AS(&ws[OFF_CNT + i], 0u);
    AS(&ws[OFF_LAB + i], (uint32_t)i);
  }
  if (gtid < 256) AS(&ws[OFF_ROOTBM + gtid], 0u);
  for (int i = gtid; i < npts; i += T) {
    float x = pts[i * 5 + 1];
    float y = pts[i * 5 + 2];
    int cx = (int)floorf((x - (-51.2f)) / 0.2f);
    int cy = (int)floorf((y - (-51.2f)) / 0.2f);
    cx = min(max(cx, 0), GRIDW - 1);
    cy = min(max(cy, 0), GRIDW - 1);
    int cell = cy * GRIDW + cx;
    atomicOr(&ws[OFF_OCC + (cell >> 5)], 1u << (cell & 31));
  }
  gsync(ws, 0);

  // ---- PB: block 0 = voxel-rank prefix (sc1 stores); blocks 1..32 = core
  //          masks (sc1 stores). occ plain reads (immutable after bar 0).
  const uint32_t* occ = ws + OFF_OCC;
  if (blockIdx.x == 0) {
    int base = tid * 32;
    uint32_t s = 0;
    for (int j = 0; j < 32; j++) s += __popc(occ[base + j]);
    int lane = tid & 63, wv = tid >> 6;
    uint32_t inc = s;
    for (int d = 1; d < 64; d <<= 1) { uint32_t t = __shfl_up(inc, d); if (lane >= d) inc += t; }
    if (lane == 63) wsum[wv] = inc;
    __syncthreads();
    uint32_t woff = 0;
    for (int k = 0; k < wv; k++) woff += wsum[k];
    uint32_t excl = woff + inc - s;
    for (int j = 0; j < 32; j++) { AS(&ws[OFF_PRE + base + j], excl); excl += __popc(occ[base + j]); }
  } else {
    int wi = gtid - 256;
    if (wi < NWORDS) {
      uint32_t cB = occ[wi];
      int y = wi >> 4, wx = wi & 15;
      uint32_t lB = wx ? occ[wi - 1] : 0u;
      uint32_t rB = (wx < 15) ? occ[wi + 1] : 0u;
      uint32_t cA = 0, lA = 0, rA = 0, cC = 0, lC = 0, rC = 0;
      if (y > 0) { int wa = wi - WPR; cA = occ[wa]; lA = wx ? occ[wa - 1] : 0u; rA = (wx < 15) ? occ[wa + 1] : 0u; }
      if (y < GRIDW - 1) { int wc = wi + WPR; cC = occ[wc]; lC = wx ? occ[wc - 1] : 0u; rC = (wx < 15) ? occ[wc + 1] : 0u; }
      uint32_t a0, a1, b0, b1, c0, c1;
      hsum(lA, cA, rA, a0, a1); hsum(lB, cB, rB, b0, b1); hsum(lC, cC, rC, c0, c1);
      AS(&ws[OFF_CM + wi], ge5(a0, a1, b0, b1, c0, c1) & cB);
    }
  }
  gsync(ws, 1);

  // ---- PC: word-level union of core-core edges (E, S, SE, SW forward) ----
  const uint32_t* cm = ws + OFF_CM;
  const uint32_t* pre = ws + OFF_PRE;
  uint32_t* lab = ws + OFF_LAB;
  for (int wi = gtid; wi < NWORDS; wi += T) {
    uint32_t cw = cm[wi];
    if (!cw) continue;
    int y = wi >> 4, wx = wi & 15;
    uint32_t cB = occ[wi];
    int rBase = pre[wi];
    uint32_t cmE = (wx < 15) ? cm[wi + 1] : 0u;
    int preE = (wx < 15) ? (int)pre[wi + 1] : 0;
    bool hasS = y < GRIDW - 1;
    uint32_t cmS = 0, occS = 0, cmSE = 0, cmSW = 0;
    int rS = 0, preSE = 0;
    if (hasS) {
      cmS = cm[wi + WPR]; occS = occ[wi + WPR]; rS = pre[wi + WPR];
      cmSE = (wx < 15) ? cm[wi + WPR + 1] : 0u;
      preSE = (wx < 15) ? (int)pre[wi + WPR + 1] : 0;
      cmSW = (wx > 0) ? cm[wi + WPR - 1] : 0u;
    }
    uint32_t bits = cw;
    while (bits) {
      int b = __ffs(bits) - 1; bits &= bits - 1;
      int r = rBase + __popc(cB & ((1u << b) - 1u));
      bool eC = (b < 31) ? ((cw >> (b + 1)) & 1) : (cmE & 1);
      if (eC) unite(lab, r, (b < 31) ? r + 1 : preE);
      if (hasS) {
        if ((cmS >> b) & 1) unite(lab, r, rS + __popc(occS & ((1u << b) - 1u)));
        bool seC = (b < 31) ? ((cmS >> (b + 1)) & 1) : (cmSE & 1);
        if (seC) unite(lab, r, (b < 31) ? rS + __popc(occS & ((2u << b) - 1u)) : preSE);
        bool swC = (b > 0) ? ((cmS >> (b - 1)) & 1) : (cmSW >> 31);
        if (swC) unite(lab, r, (b > 0) ? rS + __popc(occS & ((1u << (b - 1)) - 1u)) : rS - 1);
      }
    }
  }
  gsync(ws, 2);

  // ---- PD: word-level compress (core) + border attach + counts ----
  uint32_t* cnt = ws + OFF_CNT;
  for (int wi = gtid; wi < NWORDS; wi += T) {
    uint32_t cB = occ[wi];
    if (!cB) continue;
    int y = wi >> 4, wx = wi & 15;
    uint32_t cw = cm[wi];
    int rBase = pre[wi];
    uint32_t cmW = (wx > 0) ? cm[wi - 1] : 0u;
    uint32_t cmE = (wx < 15) ? cm[wi + 1] : 0u;
    int preE = (wx < 15) ? (int)pre[wi + 1] : 0;
    bool hasN = y > 0, hasS = y < GRIDW - 1;
    uint32_t cmN = 0, occN = 0, cmNE = 0, cmNW = 0;
    int rN = 0, preNE = 0;
    if (hasN) {
      cmN = cm[wi - WPR]; occN = occ[wi - WPR]; rN = pre[wi - WPR];
      cmNE = (wx < 15) ? cm[wi - WPR + 1] : 0u;
      preNE = (wx < 15) ? (int)pre[wi - WPR + 1] : 0;
      cmNW = (wx > 0) ? cm[wi - WPR - 1] : 0u;
    }
    uint32_t cmS = 0, occS = 0, cmSE = 0, cmSW = 0;
    int rS = 0, preSE = 0;
    if (hasS) {
      cmS = cm[wi + WPR]; occS = occ[wi + WPR]; rS = pre[wi + WPR];
      cmSE = (wx < 15) ? cm[wi + WPR + 1] : 0u;
      preSE = (wx < 15) ? (int)pre[wi + WPR + 1] : 0;
      cmSW = (wx > 0) ? cm[wi + WPR - 1] : 0u;
    }
    uint32_t bits = cB;
    while (bits) {
      int b = __ffs(bits) - 1; bits &= bits - 1;
      int r = rBase + __popc(cB & ((1u << b) - 1u));
      if ((cw >> b) & 1) {
        uint32_t root = findc(lab, r);
        AS(&lab[r], root);
        if (root == (uint32_t)r) atomicOr(&ws[OFF_ROOTBM + (r >> 5)], 1u << (r & 31));
        atomicAdd(&cnt[root], 1u);
      } else {
        uint32_t m = NONE;
        bool wC = (b > 0) ? ((cw >> (b - 1)) & 1) : (cmW >> 31);
        if (wC) m = min(m, findc(lab, (b > 0) ? r - 1 : rBase - 1));
        bool eC = (b < 31) ? ((cw >> (b + 1)) & 1) : (cmE & 1);
        if (eC) m = min(m, findc(lab, (b < 31) ? r + 1 : preE));
        if (hasN) {
          if ((cmN >> b) & 1) m = min(m, findc(lab, rN + __popc(occN & ((1u << b) - 1u))));
          bool neC = (b < 31) ? ((cmN >> (b + 1)) & 1) : (cmNE & 1);
          if (neC) m = min(m, findc(lab, (b < 31) ? rN + __popc(occN & ((2u << b) - 1u)) : preNE));
          bool nwC = (b > 0) ? ((cmN >> (b - 1)) & 1) : (cmNW >> 31);
          if (nwC) m = min(m, findc(lab, (b > 0) ? rN + __popc(occN & ((1u << (b - 1)) - 1u)) : rN - 1));
        }
        if (hasS) {
          if ((cmS >> b) & 1) m = min(m, findc(lab, rS + __popc(occS & ((1u << b) - 1u))));
          bool seC = (b < 31) ? ((cmS >> (b + 1)) & 1) : (cmSE & 1);
          if (seC) m = min(m, findc(lab, (b < 31) ? rS + __popc(occS & ((2u << b) - 1u)) : preSE));
          bool swC = (b > 0) ? ((cmS >> (b - 1)) & 1) : (cmSW >> 31);
          if (swC) m = min(m, findc(lab, (b > 0) ? rS + __popc(occS & ((1u << (b - 1)) - 1u)) : rS - 1));
        }
        AS(&lab[r], m);  // NONE => noise; border ranks never union-find parents
        if (m != NONE) atomicAdd(&cnt[m], 1u);
      }
    }
  }
  gsync(ws, 3);

  // ---- PE (ALL blocks, redundantly -> LDS): dense root numbering, keep
  //      filter (>=20 voxels); block 0 writes max kept id -> out[npts] ----
  if (tid == 0) smax = -1;
  __syncthreads();
  {
    uint32_t rb = AL(&ws[OFF_ROOTBM + tid]);
    s_rootbm[tid] = rb;
    uint32_t v = __popc(rb);
    int lane = tid & 63, wv = tid >> 6;
    uint32_t inc = v;
    for (int d = 1; d < 64; d <<= 1) { uint32_t t = __shfl_up(inc, d); if (lane >= d) inc += t; }
    if (lane == 63) wsum[wv] = inc;
    __syncthreads();
    uint32_t woff = 0;
    for (int k = 0; k < wv; k++) woff += wsum[k];
    uint32_t excl = woff + inc - v;
    s_rpre[tid] = excl;
    uint32_t keep = 0;
    int mx = -1, d = (int)excl;
    while (rb) {
      int b = __ffs(rb) - 1; rb &= rb - 1;
      int rr = tid * 32 + b;
      if (AL(&ws[OFF_CNT + rr]) >= 20u) { keep |= 1u << b; mx = d; }
      d++;
    }
    s_keep[tid] = keep;
    if (mx >= 0) atomicMax(&smax, mx);
    __syncthreads();
    if (blockIdx.x == 0 && tid == 0) out[npts] = (float)(smax + 1);
  }

  // ---- PF: scatter dense labels back to points (LDS keep/rpre/rootbm) ----
  for (int i = gtid; i < npts; i += T) {
    float x = pts[i * 5 + 1];
    float y = pts[i * 5 + 2];
    int cx = (int)floorf((x - (-51.2f)) / 0.2f);  // identical math to PA
    int cy = (int)floorf((y - (-51.2f)) / 0.2f);
    cx = min(max(cx, 0), GRIDW - 1);
    cy = min(max(cy, 0), GRIDW - 1);
    int cell = cy * GRIDW + cx;
    int wi = cell >> 5;
    int r = pre[wi] + __popc(occ[wi] & ((1u << (cell & 31)) - 1u));
    uint32_t l = AL(&lab[r]);
    float o = -1.0f;
    if (l != NONE && ((s_keep[l >> 5] >> (l & 31)) & 1)) {
      int dnum = s_rpre[l >> 5] +
                 __popc(s_rootbm[l >> 5] & ((1u << (l & 31)) - 1u));
      o = (float)dnum;
    }
    out[i] = o;
  }
}

extern "C" void kernel_launch(void* const* d_in, const int* in_sizes, int n_in,
                              void* d_out, int out_size, void* d_ws, size_t ws_size,
                              hipStream_t stream) {
  const float* pts = (const float*)d_in[0];
  int npts = in_sizes[0] / 5;  // points are (N,5) float32
  uint32_t* ws = (uint32_t*)d_ws;
  float* out = (float*)d_out;
  hipMemsetAsync(d_ws, 0, MEMSET_BYTES, stream);  // occ + barrier counters
  k_all<<<NB, 256, 0, stream>>>(pts, ws, out, npts);
}

// Round 4
// 218.762 us; speedup vs baseline: 1.0274x; 1.0274x over previous
//
#include <hip/hip_runtime.h>
#include <stdint.h>

// DBSCAN-on-voxel-grid, exact port of the JAX reference for batch_size==1.
// Grid 512x512, eps=1.5 => 8-connected adjacency, min_samples=5 (voxels,
// incl. self), clusters with <20 voxels dropped.
//
// R10 = ONE workgroup (1024 threads, 16 waves, one CU), ONE dispatch.
// Rationale (R8/R9 post-mortem): total state is tiny; multi-block designs
// pay either multi-dispatch latency (R6: 96us) or device-barrier +
// coherent-access tax (R8/R9: every union-find hop at agent scope ~0.35us,
// serial dependent chains => 120-170us). Single block:
//  - lab[] (union-find, the latency-critical random-chase target) lives in
//    LDS: ~25ns/hop, atomicCAS on shared, same guarded-monotone algorithm.
//  - all phase sync is __syncthreads() (~100ns, one CU => trivially coherent,
//    zero cross-XCD concerns).
//  - occ/cm/pre/cnt in global ws (128KB, L1/L2-hot plain loads).
//    L1-staleness discipline: occ/cnt are zeroed via atomicExch (L2-direct,
//    no L1 line allocated) and updated only by atomics; their first plain
//    read is after the last atomic write + barrier, so L1 can only ever
//    fill with final data. cm/pre are plain-written once and never touched
//    by atomics afterwards.
//  - no hipMemsetAsync: all init in-kernel.

#define GRIDW 512
#define WPR 16        // bitmap words per row
#define NWORDS 8192   // 512*512/32
#define NONE 0xFFFFFFFFu
#define BS 1024       // single workgroup of 16 waves

// ---- global ws layout (uint32 units) ----
#define OFF_OCC 0      // 8192: occupancy bitmap (atomicExch-zeroed in P0)
#define OFF_CNT 8192   // 8192: per-root voxel counts (atomicExch-zeroed in P0)
#define OFF_CM  16384  // 8192: core mask per word
#define OFF_PRE 24576  // 8192: exclusive voxel-rank prefix per word

// per-position horizontal (west+self+east) 2-bit counts for a row of 32 cells
__device__ __forceinline__ void hsum(uint32_t l, uint32_t c, uint32_t r,
                                     uint32_t& h0, uint32_t& h1) {
  uint32_t Wb = (c << 1) | (l >> 31);
  uint32_t Eb = (c >> 1) | (r << 31);
  h0 = Wb ^ c ^ Eb;
  h1 = (Wb & c) | (Eb & (Wb ^ c));
}

// per-position (sum of three 2-bit row counts) >= 5 (bit-sliced adders)
__device__ __forceinline__ uint32_t ge5(uint32_t a0, uint32_t a1, uint32_t b0,
                                        uint32_t b1, uint32_t c0, uint32_t c1) {
  uint32_t u0 = a0 ^ b0, cy = a0 & b0;
  uint32_t t = a1 ^ b1;
  uint32_t u1 = t ^ cy;
  uint32_t u2 = (a1 & b1) | (cy & t);
  uint32_t v0 = u0 ^ c0, k0 = u0 & c0;
  uint32_t t2 = u1 ^ c1;
  uint32_t v1 = t2 ^ k0;
  uint32_t k1 = (u1 & c1) | (k0 & t2);
  uint32_t v2 = u2 ^ k1;
  uint32_t v3 = u2 & k1;
  return v3 | (v2 & (v1 | v0));  // count in {5..9}
}

// LDS union-find. Links are only ever LOWERED (CAS writes r only while
// r < current link), preserving the monotone-decreasing invariant =>
// no cycles, guaranteed termination. All ops on shared memory (one CU,
// hardware-coherent, ds_* latency).
__device__ __forceinline__ uint32_t lread(uint32_t* L, uint32_t i) {
  return __hip_atomic_load(&L[i], __ATOMIC_RELAXED, __HIP_MEMORY_SCOPE_WORKGROUP);
}

__device__ __forceinline__ uint32_t findc(uint32_t* L, uint32_t x) {
  uint32_t r = x, p = lread(L, r);
  while (p != r) { r = p; p = lread(L, r); }
  while (x > r) {
    uint32_t nx = lread(L, x);
    if (nx <= r) break;          // someone already lowered it at least as far
    atomicCAS(&L[x], nx, r);     // best effort, only writes a smaller value
    x = nx;
  }
  return r;
}

// link larger root under smaller => final root == min core rank of component
__device__ __forceinline__ void unite(uint32_t* L, uint32_t a, uint32_t b) {
  for (;;) {
    a = findc(L, a);
    b = findc(L, b);
    if (a == b) return;
    uint32_t lo = min(a, b), hi = max(a, b);
    if (atomicCAS(&L[hi], hi, lo) == hi) return;  // hi still root => linked
    a = lo; b = hi;
  }
}

__global__ __launch_bounds__(BS, 1) void k_all(const float* __restrict__ pts,
                                               uint32_t* __restrict__ ws,
                                               float* __restrict__ out,
                                               int npts) {
  __shared__ uint32_t s_lab[NWORDS];   // union-find / final labels (by rank)
  __shared__ uint32_t s_rootbm[256];
  __shared__ uint32_t s_keep[256];
  __shared__ uint32_t s_rpre[256];
  __shared__ uint32_t wsum[16];
  const int tid = threadIdx.x;

  // ---- P0: zero occ/cnt (atomicExch: L2-direct, never allocates L1),
  //          init LDS union-find, zero rootbm ----
  for (int i = tid; i < NWORDS; i += BS) {
    atomicExch(&ws[OFF_OCC + i], 0u);
    atomicExch(&ws[OFF_CNT + i], 0u);
    s_lab[i] = (uint32_t)i;
  }
  if (tid < 256) s_rootbm[tid] = 0u;
  __syncthreads();

  // ---- P1: voxelize points -> occupancy bits (identical f32 ops to jnp) ----
  for (int i = tid; i < npts; i += BS) {
    float x = pts[i * 5 + 1];
    float y = pts[i * 5 + 2];
    int cx = (int)floorf((x - (-51.2f)) / 0.2f);
    int cy = (int)floorf((y - (-51.2f)) / 0.2f);
    cx = min(max(cx, 0), GRIDW - 1);
    cy = min(max(cy, 0), GRIDW - 1);
    int cell = cy * GRIDW + cx;
    atomicOr(&ws[OFF_OCC + (cell >> 5)], 1u << (cell & 31));
  }
  __syncthreads();

  // ---- P2: core masks + voxel-rank prefix (each thread: 8 contiguous
  //          words; 16-wave shfl scan + LDS partials for the prefix) ----
  const uint32_t* occ = ws + OFF_OCC;
  {
    int base = tid * 8;
    uint32_t s = 0;
    for (int j = 0; j < 8; j++) {
      int wi = base + j;
      uint32_t cB = occ[wi];
      s += __popc(cB);
      int y = wi >> 4, wx = wi & 15;
      uint32_t lB = wx ? occ[wi - 1] : 0u;
      uint32_t rB = (wx < 15) ? occ[wi + 1] : 0u;
      uint32_t cA = 0, lA = 0, rA = 0, cC = 0, lC = 0, rC = 0;
      if (y > 0) { int wa = wi - WPR; cA = occ[wa]; lA = wx ? occ[wa - 1] : 0u; rA = (wx < 15) ? occ[wa + 1] : 0u; }
      if (y < GRIDW - 1) { int wc = wi + WPR; cC = occ[wc]; lC = wx ? occ[wc - 1] : 0u; rC = (wx < 15) ? occ[wc + 1] : 0u; }
      uint32_t a0, a1, b0, b1, c0, c1;
      hsum(lA, cA, rA, a0, a1); hsum(lB, cB, rB, b0, b1); hsum(lC, cC, rC, c0, c1);
      ws[OFF_CM + wi] = ge5(a0, a1, b0, b1, c0, c1) & cB;
    }
    int lane = tid & 63, wv = tid >> 6;
    uint32_t inc = s;
    for (int d = 1; d < 64; d <<= 1) { uint32_t t = __shfl_up(inc, d); if (lane >= d) inc += t; }
    if (lane == 63) wsum[wv] = inc;
    __syncthreads();
    uint32_t woff = 0;
    for (int k = 0; k < wv; k++) woff += wsum[k];
    uint32_t excl = woff + inc - s;
    for (int j = 0; j < 8; j++) { ws[OFF_PRE + base + j] = excl; excl += __popc(occ[base + j]); }
  }
  __syncthreads();

  // ---- P3: word-level union of core-core edges (E, S, SE, SW forward) ----
  const uint32_t* cm = ws + OFF_CM;
  const uint32_t* pre = ws + OFF_PRE;
  for (int wi = tid; wi < NWORDS; wi += BS) {
    uint32_t cw = cm[wi];
    if (!cw) continue;
    int y = wi >> 4, wx = wi & 15;
    uint32_t cB = occ[wi];
    int rBase = pre[wi];
    uint32_t cmE = (wx < 15) ? cm[wi + 1] : 0u;
    int preE = (wx < 15) ? (int)pre[wi + 1] : 0;
    bool hasS = y < GRIDW - 1;
    uint32_t cmS = 0, occS = 0, cmSE = 0, cmSW = 0;
    int rS = 0, preSE = 0;
    if (hasS) {
      cmS = cm[wi + WPR]; occS = occ[wi + WPR]; rS = pre[wi + WPR];
      cmSE = (wx < 15) ? cm[wi + WPR + 1] : 0u;
      preSE = (wx < 15) ? (int)pre[wi + WPR + 1] : 0;
      cmSW = (wx > 0) ? cm[wi + WPR - 1] : 0u;
    }
    uint32_t bits = cw;
    while (bits) {
      int b = __ffs(bits) - 1; bits &= bits - 1;
      int r = rBase + __popc(cB & ((1u << b) - 1u));
      bool eC = (b < 31) ? ((cw >> (b + 1)) & 1) : (cmE & 1);
      if (eC) unite(s_lab, r, (b < 31) ? r + 1 : preE);
      if (hasS) {
        if ((cmS >> b) & 1) unite(s_lab, r, rS + __popc(occS & ((1u << b) - 1u)));
        bool seC = (b < 31) ? ((cmS >> (b + 1)) & 1) : (cmSE & 1);
        if (seC) unite(s_lab, r, (b < 31) ? rS + __popc(occS & ((2u << b) - 1u)) : preSE);
        bool swC = (b > 0) ? ((cmS >> (b - 1)) & 1) : (cmSW >> 31);
        if (swC) unite(s_lab, r, (b > 0) ? rS + __popc(occS & ((1u << (b - 1)) - 1u)) : rS - 1);
      }
    }
  }
  __syncthreads();

  // ---- P4: word-level compress (core) + border attach + counts ----
  uint32_t* cnt = ws + OFF_CNT;
  for (int wi = tid; wi < NWORDS; wi += BS) {
    uint32_t cB = occ[wi];
    if (!cB) continue;
    int y = wi >> 4, wx = wi & 15;
    uint32_t cw = cm[wi];
    int rBase = pre[wi];
    uint32_t cmW = (wx > 0) ? cm[wi - 1] : 0u;
    uint32_t cmE = (wx < 15) ? cm[wi + 1] : 0u;
    int preE = (wx < 15) ? (int)pre[wi + 1] : 0;
    bool hasN = y > 0, hasS = y < GRIDW - 1;
    uint32_t cmN = 0, occN = 0, cmNE = 0, cmNW = 0;
    int rN = 0, preNE = 0;
    if (hasN) {
      cmN = cm[wi - WPR]; occN = occ[wi - WPR]; rN = pre[wi - WPR];
      cmNE = (wx < 15) ? cm[wi - WPR + 1] : 0u;
      preNE = (wx < 15) ? (int)pre[wi - WPR + 1] : 0;
      cmNW = (wx > 0) ? cm[wi - WPR - 1] : 0u;
    }
    uint32_t cmS = 0, occS = 0, cmSE = 0, cmSW = 0;
    int rS = 0, preSE = 0;
    if (hasS) {
      cmS = cm[wi + WPR]; occS = occ[wi + WPR]; rS = pre[wi + WPR];
      cmSE = (wx < 15) ? cm[wi + WPR + 1] : 0u;
      preSE = (wx < 15) ? (int)pre[wi + WPR + 1] : 0;
      cmSW = (wx > 0) ? cm[wi + WPR - 1] : 0u;
    }
    uint32_t bits = cB;
    while (bits) {
      int b = __ffs(bits) - 1; bits &= bits - 1;
      int r = rBase + __popc(cB & ((1u << b) - 1u));
      if ((cw >> b) & 1) {
        uint32_t root = findc(s_lab, r);
        s_lab[r] = root;
        if (root == (uint32_t)r) atomicOr(&s_rootbm[r >> 5], 1u << (r & 31));
        atomicAdd(&cnt[root], 1u);
      } else {
        uint32_t m = NONE;
        bool wC = (b > 0) ? ((cw >> (b - 1)) & 1) : (cmW >> 31);
        if (wC) m = min(m, findc(s_lab, (b > 0) ? r - 1 : rBase - 1));
        bool eC = (b < 31) ? ((cw >> (b + 1)) & 1) : (cmE & 1);
        if (eC) m = min(m, findc(s_lab, (b < 31) ? r + 1 : preE));
        if (hasN) {
          if ((cmN >> b) & 1) m = min(m, findc(s_lab, rN + __popc(occN & ((1u << b) - 1u))));
          bool neC = (b < 31) ? ((cmN >> (b + 1)) & 1) : (cmNE & 1);
          if (neC) m = min(m, findc(s_lab, (b < 31) ? rN + __popc(occN & ((2u << b) - 1u)) : preNE));
          bool nwC = (b > 0) ? ((cmN >> (b - 1)) & 1) : (cmNW >> 31);
          if (nwC) m = min(m, findc(s_lab, (b > 0) ? rN + __popc(occN & ((1u << (b - 1)) - 1u)) : rN - 1));
        }
        if (hasS) {
          if ((cmS >> b) & 1) m = min(m, findc(s_lab, rS + __popc(occS & ((1u << b) - 1u))));
          bool seC = (b < 31) ? ((cmS >> (b + 1)) & 1) : (cmSE & 1);
          if (seC) m = min(m, findc(s_lab, (b < 31) ? rS + __popc(occS & ((2u << b) - 1u)) : preSE));
          bool swC = (b > 0) ? ((cmS >> (b - 1)) & 1) : (cmSW >> 31);
          if (swC) m = min(m, findc(s_lab, (b > 0) ? rS + __popc(occS & ((1u << (b - 1)) - 1u)) : rS - 1));
        }
        s_lab[r] = m;  // NONE => noise; border ranks never union-find parents
        if (m != NONE) atomicAdd(&cnt[m], 1u);
      }
    }
  }
  __syncthreads();

  // ---- P5 (wave 0 only, shfl-scan, no barriers inside): dense root
  //      numbering, keep filter (>=20 voxels), max kept id -> out[npts] ----
  if (tid < 64) {
    int lane = tid;
    uint32_t rb[4];
    uint32_t v = 0;
    for (int j = 0; j < 4; j++) { rb[j] = s_rootbm[lane * 4 + j]; v += __popc(rb[j]); }
    uint32_t inc = v;
    for (int d = 1; d < 64; d <<= 1) { uint32_t t = __shfl_up(inc, d); if (lane >= d) inc += t; }
    int d = (int)(inc - v);  // exclusive prefix of root counts
    int mx = -1;
    for (int j = 0; j < 4; j++) {
      int w = lane * 4 + j;
      s_rpre[w] = (uint32_t)d;
      uint32_t bits = rb[j];
      uint32_t keep = 0;
      while (bits) {
        int b = __ffs(bits) - 1; bits &= bits - 1;
        int rr = w * 32 + b;
        if (cnt[rr] >= 20u) { keep |= 1u << b; mx = d; }
        d++;
      }
      s_keep[w] = keep;
    }
    for (int o = 32; o; o >>= 1) mx = max(mx, __shfl_xor(mx, o));
    if (lane == 0) out[npts] = (float)(mx + 1);
  }
  __syncthreads();

  // ---- P6: scatter dense labels back to points ----
  for (int i = tid; i < npts; i += BS) {
    float x = pts[i * 5 + 1];
    float y = pts[i * 5 + 2];
    int cx = (int)floorf((x - (-51.2f)) / 0.2f);  // identical math to P1
    int cy = (int)floorf((y - (-51.2f)) / 0.2f);
    cx = min(max(cx, 0), GRIDW - 1);
    cy = min(max(cy, 0), GRIDW - 1);
    int cell = cy * GRIDW + cx;
    int wi = cell >> 5;
    int r = pre[wi] + __popc(occ[wi] & ((1u << (cell & 31)) - 1u));
    uint32_t l = s_lab[r];
    float o = -1.0f;
    if (l != NONE && ((s_keep[l >> 5] >> (l & 31)) & 1)) {
      int dnum = s_rpre[l >> 5] +
                 __popc(s_rootbm[l >> 5] & ((1u << (l & 31)) - 1u));
      o = (float)dnum;
    }
    out[i] = o;
  }
}

extern "C" void kernel_launch(void* const* d_in, const int* in_sizes, int n_in,
                              void* d_out, int out_size, void* d_ws, size_t ws_size,
                              hipStream_t stream) {
  const float* pts = (const float*)d_in[0];
  int npts = in_sizes[0] / 5;  // points are (N,5) float32
  uint32_t* ws = (uint32_t*)d_ws;
  float* out = (float*)d_out;
  k_all<<<1, BS, 0, stream>>>(pts, ws, out, npts);
}

// Round 5
// 192.155 us; speedup vs baseline: 1.1696x; 1.1385x over previous
//
#include <hip/hip_runtime.h>
#include <stdint.h>

// DBSCAN-on-voxel-grid, exact port of the JAX reference for batch_size==1.
// Grid 512x512, eps=1.5 => 8-connected adjacency, min_samples=5 (voxels,
// incl. self), clusters with <20 voxels dropped.
//
// R11: back to the PROVEN multi-kernel structure (R6, 96.5us) after three
// fusion regressions (R7 coop-launch 253, R9 sc1-tax 225, R10 one-CU 219).
// Lesson: kernel-boundary coherence + wide grids beat any device barrier
// here; the fixed ~39.4us harness poison-fill is inside dur_us, so only
// pipeline time X matters. R11 cuts R6's X (~55us) by:
//  - CELL-ID union-find (lab[cell], 1MB, L2-hot) instead of rank-based:
//    deletes the global prefix scan (k_scan_cm dispatch) and every
//    popc-rank computation. Rank is strictly monotone in cell id, so
//    min-root selection and sorted dense numbering are unchanged.
//  - k_merge recomputes core masks from occ bit-slices and STORES cm
//    for k_cb to reuse (one array write, no extra dispatch).
//  - k_finish folded into k_cb as a last-block ticket tail (reads only
//    atomic-written cnt/rootbm; block atomics are vmcnt-drained by
//    __syncthreads before the ticket add -> globally complete first).
//  - 5 dispatches total: memset, init+vox, merge, cb+finish, scatter.

#define GRIDW 512
#define WPR 16        // bitmap words per row
#define NWORDS 8192   // 512*512/32
#define NCELLS 262144
#define NONE 0xFFFFFFFFu
#define NB_CB 32      // k_cb blocks (8192 words / 256)

// ---- ws layout (uint32 units). [occ|cnt|rootbm|ticket] zeroed by memset.
#define OFF_OCC    0        // 8192: occupancy bitmap
#define OFF_CNT    8192     // 262144: per-root-cell voxel counts
#define OFF_ROOTBM 270336   // 8192: root bitmap (by cell id)
#define OFF_TICKET 278528   // 1 (+pad to 16)
#define MEMSET_WORDS 278544
#define OFF_LAB    278560   // 262144: union-find labels (by cell id)
#define OFF_CM     540704   // 8192: core mask per word (written by k_merge)
#define OFF_KEEP   548896   // 8192: keep bitmap (by root cell id)
#define OFF_RPRE   557088   // 8192: exclusive root-rank prefix per word

// per-position horizontal (west+self+east) 2-bit counts for a row of 32 cells
__device__ __forceinline__ void hsum(uint32_t l, uint32_t c, uint32_t r,
                                     uint32_t& h0, uint32_t& h1) {
  uint32_t Wb = (c << 1) | (l >> 31);
  uint32_t Eb = (c >> 1) | (r << 31);
  h0 = Wb ^ c ^ Eb;
  h1 = (Wb & c) | (Eb & (Wb ^ c));
}

// per-position (sum of three 2-bit row counts) >= 5 (bit-sliced adders)
__device__ __forceinline__ uint32_t ge5(uint32_t a0, uint32_t a1, uint32_t b0,
                                        uint32_t b1, uint32_t c0, uint32_t c1) {
  uint32_t u0 = a0 ^ b0, cy = a0 & b0;
  uint32_t t = a1 ^ b1;
  uint32_t u1 = t ^ cy;
  uint32_t u2 = (a1 & b1) | (cy & t);
  uint32_t v0 = u0 ^ c0, k0 = u0 & c0;
  uint32_t t2 = u1 ^ c1;
  uint32_t v1 = t2 ^ k0;
  uint32_t k1 = (u1 & c1) | (k0 & t2);
  uint32_t v2 = u2 ^ k1;
  uint32_t v3 = u2 & k1;
  return v3 | (v2 & (v1 | v0));  // count in {5..9}
}

__device__ __forceinline__ uint32_t aread(uint32_t* p) {
  return __hip_atomic_load(p, __ATOMIC_RELAXED, __HIP_MEMORY_SCOPE_AGENT);
}

// find root with guarded path compression: links are only ever LOWERED
// (write r into L[x] only while r < current link), preserving the
// monotone-decreasing invariant => no cycles, guaranteed termination.
__device__ __forceinline__ uint32_t findc(uint32_t* L, uint32_t x) {
  uint32_t r = x, p = aread(&L[r]);
  while (p != r) { r = p; p = aread(&L[r]); }
  while (x > r) {
    uint32_t nx = aread(&L[x]);
    if (nx <= r) break;          // someone already lowered it at least as far
    atomicCAS(&L[x], nx, r);     // best effort, only writes a smaller value
    x = nx;
  }
  return r;
}

// link larger root under smaller => final root == min core CELL of component
__device__ __forceinline__ void unite(uint32_t* L, uint32_t a, uint32_t b) {
  for (;;) {
    a = findc(L, a);
    b = findc(L, b);
    if (a == b) return;
    uint32_t lo = min(a, b), hi = max(a, b);
    if (atomicCAS(&L[hi], hi, lo) == hi) return;  // hi still root => linked
    a = lo; b = hi;
  }
}

// K1: lab[c]=c init (uint4 stores) + voxelize points (identical f32 ops)
__global__ __launch_bounds__(256) void k_init_vox(const float* __restrict__ pts,
                                                  uint32_t* __restrict__ ws,
                                                  int npts) {
  int gtid = blockIdx.x * 256 + threadIdx.x;
  const int T = 64 * 256;
  for (int j = gtid; j < NCELLS / 4; j += T) {
    uint32_t i = (uint32_t)j * 4u;
    *reinterpret_cast<uint4*>(&ws[OFF_LAB + i]) =
        make_uint4(i, i + 1u, i + 2u, i + 3u);
  }
  for (int i = gtid; i < npts; i += T) {
    float x = pts[i * 5 + 1];
    float y = pts[i * 5 + 2];
    int cx = (int)floorf((x - (-51.2f)) / 0.2f);
    int cy = (int)floorf((y - (-51.2f)) / 0.2f);
    cx = min(max(cx, 0), GRIDW - 1);
    cy = min(max(cy, 0), GRIDW - 1);
    int cell = cy * GRIDW + cx;
    atomicOr(&ws[OFF_OCC + (cell >> 5)], 1u << (cell & 31));
  }
}

// K2: per-word: compute cm(self) from occ bit-slices, store it; compute
// cm(E/S/SE/SW) locally and union core-core forward edges with CELL ids.
__global__ __launch_bounds__(256) void k_merge(uint32_t* __restrict__ ws) {
  int wi = blockIdx.x * 256 + threadIdx.x;  // 8192 threads, one word each
  const uint32_t* occ = ws + OFF_OCC;
  uint32_t* lab = ws + OFF_LAB;
  uint32_t cB = occ[wi];
  if (!cB) { ws[OFF_CM + wi] = 0u; return; }
  int y = wi >> 4, wx = wi & 15;
  // occ neighborhood rows y-1..y+2 x cols wx-2..wx+2 (zero-guarded)
  uint32_t O[4][5];
#pragma unroll
  for (int r = 0; r < 4; r++) {
    int yy = y - 1 + r;
#pragma unroll
    for (int k = 0; k < 5; k++) {
      int xx = wx - 2 + k;
      O[r][k] = (yy >= 0 && yy < GRIDW && xx >= 0 && xx < WPR)
                    ? occ[yy * WPR + xx] : 0u;
    }
  }
  uint32_t h0[4][3], h1[4][3];
#pragma unroll
  for (int r = 0; r < 4; r++)
#pragma unroll
    for (int c = 0; c < 3; c++)
      hsum(O[r][c], O[r][c + 1], O[r][c + 2], h0[r][c], h1[r][c]);
  // cm(row rc, col cc): rc in {1,2} => y,y+1 ; cc in {0,1,2} => wx-1..wx+1
#define CM(rc, cc) (ge5(h0[(rc)-1][cc], h1[(rc)-1][cc], h0[rc][cc], h1[rc][cc], \
                        h0[(rc)+1][cc], h1[(rc)+1][cc]) & O[rc][(cc)+1])
  uint32_t cmC = CM(1, 1);
  ws[OFF_CM + wi] = cmC;
  if (!cmC) return;
  uint32_t cmE = CM(1, 2);   // auto-0 at wx==15 (guarded loads)
  uint32_t cmS = CM(2, 1);   // auto-0 at y==511
  uint32_t cmSE = CM(2, 2);
  uint32_t cmSW = CM(2, 0);
#undef CM
  uint32_t bits = cmC;
  while (bits) {
    int b = __ffs(bits) - 1; bits &= bits - 1;
    uint32_t cell = (uint32_t)wi * 32u + (uint32_t)b;
    bool eC = (b < 31) ? ((cmC >> (b + 1)) & 1) : (cmE & 1);
    if (eC) unite(lab, cell, cell + 1);
    if ((cmS >> b) & 1) unite(lab, cell, cell + 512);
    bool seC = (b < 31) ? ((cmS >> (b + 1)) & 1) : (cmSE & 1);
    if (seC) unite(lab, cell, cell + 513);
    bool swC = (b > 0) ? ((cmS >> (b - 1)) & 1) : (cmSW >> 31);
    if (swC) unite(lab, cell, cell + 511);
  }
}

// K3: per-word compress (core) + border attach + counts; last block runs
// the finish phase (dense root numbering over rootbm, keep filter, max id).
__global__ __launch_bounds__(256) void k_cb(uint32_t* __restrict__ ws,
                                            float* __restrict__ out, int npts) {
  const int tid = threadIdx.x;
  int wi = blockIdx.x * 256 + tid;
  const uint32_t* occ = ws + OFF_OCC;
  const uint32_t* cm = ws + OFF_CM;
  uint32_t* lab = ws + OFF_LAB;
  uint32_t* cnt = ws + OFF_CNT;
  __shared__ int slast;
  __shared__ uint32_t wsum[4];
  __shared__ int smax;

  uint32_t cB = occ[wi];
  if (cB) {
    int y = wi >> 4, wx = wi & 15;
    uint32_t cw = cm[wi];
    uint32_t cmW = (wx > 0) ? cm[wi - 1] : 0u;
    uint32_t cmE = (wx < 15) ? cm[wi + 1] : 0u;
    bool hasN = y > 0, hasS = y < GRIDW - 1;
    uint32_t cmN = 0, cmNE = 0, cmNW = 0, cmS = 0, cmSE = 0, cmSW = 0;
    if (hasN) {
      cmN = cm[wi - WPR];
      cmNE = (wx < 15) ? cm[wi - WPR + 1] : 0u;
      cmNW = (wx > 0) ? cm[wi - WPR - 1] : 0u;
    }
    if (hasS) {
      cmS = cm[wi + WPR];
      cmSE = (wx < 15) ? cm[wi + WPR + 1] : 0u;
      cmSW = (wx > 0) ? cm[wi + WPR - 1] : 0u;
    }
    uint32_t bits = cB;
    while (bits) {
      int b = __ffs(bits) - 1; bits &= bits - 1;
      uint32_t cell = (uint32_t)wi * 32u + (uint32_t)b;
      if ((cw >> b) & 1) {
        uint32_t root = findc(lab, cell);
        lab[cell] = root;  // same final value as any concurrent compression
        if (root == cell) atomicOr(&ws[OFF_ROOTBM + (root >> 5)], 1u << (root & 31));
        atomicAdd(&cnt[root], 1u);
      } else {
        uint32_t m = NONE;
        bool wC = (b > 0) ? ((cw >> (b - 1)) & 1) : (cmW >> 31);
        if (wC) m = min(m, findc(lab, cell - 1));
        bool eC = (b < 31) ? ((cw >> (b + 1)) & 1) : (cmE & 1);
        if (eC) m = min(m, findc(lab, cell + 1));
        if ((cmN >> b) & 1) m = min(m, findc(lab, cell - 512));
        bool neC = (b < 31) ? ((cmN >> (b + 1)) & 1) : (cmNE & 1);
        if (neC) m = min(m, findc(lab, cell - 511));
        bool nwC = (b > 0) ? ((cmN >> (b - 1)) & 1) : (cmNW >> 31);
        if (nwC) m = min(m, findc(lab, cell - 513));
        if ((cmS >> b) & 1) m = min(m, findc(lab, cell + 512));
        bool seC = (b < 31) ? ((cmS >> (b + 1)) & 1) : (cmSE & 1);
        if (seC) m = min(m, findc(lab, cell + 513));
        bool swC = (b > 0) ? ((cmS >> (b - 1)) & 1) : (cmSW >> 31);
        if (swC) m = min(m, findc(lab, cell + 511));
        lab[cell] = m;  // NONE => noise; borders are never union-find parents
        if (m != NONE) atomicAdd(&cnt[m], 1u);
      }
    }
  }
  // ---- ticket: all block atomics are complete (vmcnt-drained) before the
  // ticket add issues; last block then reads only atomic-written data.
  __syncthreads();
  if (tid == 0) {
    slast = (atomicAdd(&ws[OFF_TICKET], 1u) == (uint32_t)(NB_CB - 1));
    smax = -1;
  }
  __syncthreads();
  if (!slast) return;
  // ---- finish (256 threads): dense numbering of roots (ALL roots, sorted
  // by cell id), keep = cnt>=20, max kept dense id -> out[npts].
  {
    uint32_t s = 0;
    int base = tid * 32;
    for (int j = 0; j < 32; j++) s += __popc(ws[OFF_ROOTBM + base + j]);
    int lane = tid & 63, wv = tid >> 6;
    uint32_t inc = s;
    for (int d = 1; d < 64; d <<= 1) { uint32_t t = __shfl_up(inc, d); if (lane >= d) inc += t; }
    if (lane == 63) wsum[wv] = inc;
    __syncthreads();
    uint32_t woff = 0;
    for (int k = 0; k < wv; k++) woff += wsum[k];
    int d = (int)(woff + inc - s);
    int mx = -1;
    for (int j = 0; j < 32; j++) {
      int w = base + j;
      uint32_t rb = ws[OFF_ROOTBM + w];
      ws[OFF_RPRE + w] = (uint32_t)d;
      uint32_t keep = 0;
      while (rb) {
        int b = __ffs(rb) - 1; rb &= rb - 1;
        uint32_t rr = (uint32_t)w * 32u + (uint32_t)b;
        if (cnt[rr] >= 20u) { keep |= 1u << b; mx = d; }
        d++;
      }
      ws[OFF_KEEP + w] = keep;
    }
    if (mx >= 0) atomicMax(&smax, mx);
    __syncthreads();
    if (tid == 0) out[npts] = (float)(smax + 1);
  }
}

// K4: scatter dense labels back to points (pure lookups, no rank math)
__global__ __launch_bounds__(256) void k_scatter(const float* __restrict__ pts,
                                                 const uint32_t* __restrict__ ws,
                                                 float* __restrict__ out,
                                                 int npts) {
  int i = blockIdx.x * 256 + threadIdx.x;
  if (i >= npts) return;
  float x = pts[i * 5 + 1];
  float y = pts[i * 5 + 2];
  int cx = (int)floorf((x - (-51.2f)) / 0.2f);  // identical math to k_init_vox
  int cy = (int)floorf((y - (-51.2f)) / 0.2f);
  cx = min(max(cx, 0), GRIDW - 1);
  cy = min(max(cy, 0), GRIDW - 1);
  uint32_t cell = (uint32_t)(cy * GRIDW + cx);
  uint32_t l = ws[OFF_LAB + cell];
  float o = -1.0f;
  if (l != NONE && ((ws[OFF_KEEP + (l >> 5)] >> (l & 31)) & 1)) {
    int dnum = (int)ws[OFF_RPRE + (l >> 5)] +
               __popc(ws[OFF_ROOTBM + (l >> 5)] & ((1u << (l & 31)) - 1u));
    o = (float)dnum;
  }
  out[i] = o;
}

extern "C" void kernel_launch(void* const* d_in, const int* in_sizes, int n_in,
                              void* d_out, int out_size, void* d_ws, size_t ws_size,
                              hipStream_t stream) {
  const float* pts = (const float*)d_in[0];
  int npts = in_sizes[0] / 5;  // points are (N,5) float32
  uint32_t* ws = (uint32_t*)d_ws;
  float* out = (float*)d_out;
  int pblocks = (npts + 255) / 256;
  hipMemsetAsync(d_ws, 0, MEMSET_WORDS * 4, stream);  // occ|cnt|rootbm|ticket
  k_init_vox<<<64, 256, 0, stream>>>(pts, ws, npts);
  k_merge<<<NWORDS / 256, 256, 0, stream>>>(ws);
  k_cb<<<NB_CB, 256, 0, stream>>>(ws, out, npts);
  k_scatter<<<pblocks, 256, 0, stream>>>(pts, ws, out, npts);
}

// Round 6
// 123.582 us; speedup vs baseline: 1.8186x; 1.5549x over previous
//
#include <hip/hip_runtime.h>
#include <stdint.h>

// DBSCAN-on-voxel-grid, exact port of the JAX reference for batch_size==1.
// Grid 512x512, eps=1.5 => 8-connected adjacency, min_samples=5 (voxels,
// incl. self), clusters with <20 voxels dropped.
//
// R12: R11 post-mortem: per-WORD k_cb serialized 20-32 bit-iterations x 8
// dependent L2 chases in single threads => 73us alone (Occ 0.35%, VALUBusy
// 0.13% = pure un-hidden latency). Rule confirmed all session:
// dur ~= 39.4us harness poison-fill + X; X is minimized by WIDE grids +
// kernel-boundary coherence + few dispatches (R6), never by concentrating
// dependent chases (R10 one-CU, R11 per-word).
// R12 keeps R11's wins (cell-id union-find => no prefix scan; folded
// finish; 5 dispatches) and restores per-CELL parallelism everywhere:
//  - core status computed SCALAR on the fly from occ (is_core: 3x3 bit
//    window sum >= 5; ~6 L1-hot loads) -- deletes the cm array and the
//    per-word bit-sliced kernel entirely.
//  - k_union / k_cb: 1024 blocks x 256 threads, one CELL per thread;
//    the <=8 chases of each occupied cell run in their own thread (TLP
//    hides ~200cyc L2 hops).
//  - all init (lab/cnt/rootbm/ticket) via plain vectorized stores in
//    k_init_vox; kernel-end L2 writeback publishes them (R6 mechanism).
// 5 dispatches: memset(occ 32KB), init+vox, union, cb+finish, scatter.

#define GRIDW 512
#define WPR 16        // bitmap words per row
#define NWORDS 8192   // 512*512/32
#define NCELLS 262144
#define NONE 0xFFFFFFFFu
#define NB_CB 1024    // k_cb blocks (NCELLS/256)

// ---- ws layout (uint32 units). occ zeroed by memset; rest by k_init_vox.
#define OFF_OCC    0        // 8192: occupancy bitmap
#define OFF_CNT    8192     // 262144: per-root-cell voxel counts
#define OFF_ROOTBM 270336   // 8192: root bitmap (by cell id)
#define OFF_TICKET 278528   // 1 (+pad)
#define OFF_LAB    278560   // 262144: union-find labels (by cell id)
#define OFF_KEEP   540704   // 8192: keep bitmap (by root cell id)
#define OFF_RPRE   548896   // 8192: exclusive root-rank prefix per word

__device__ __forceinline__ bool occbit(const uint32_t* occ, int x, int y) {
  return (occ[y * WPR + (x >> 5)] >> (x & 31)) & 1u;
}

// sum of occ bits (x-1..x+1, y), boundary-clipped; caller guarantees x in range
__device__ __forceinline__ uint32_t row3(const uint32_t* occ, int x, int y) {
  if ((unsigned)y >= GRIDW) return 0u;
  const uint32_t* row = occ + y * WPR;
  int w = x >> 5, b = x & 31;
  uint32_t c = row[w];
  uint32_t s = (c >> b) & 1u;
  s += (b > 0) ? ((c >> (b - 1)) & 1u) : ((x > 0) ? (row[w - 1] >> 31) : 0u);
  s += (b < 31) ? ((c >> (b + 1)) & 1u) : ((x < GRIDW - 1) ? (row[w + 1] & 1u) : 0u);
  return s;
}

// sklearn-equivalent core test: occupied && >=5 occupied voxels in 3x3 window
__device__ __forceinline__ bool is_core(const uint32_t* occ, int x, int y) {
  if (!occbit(occ, x, y)) return false;
  return row3(occ, x, y - 1) + row3(occ, x, y) + row3(occ, x, y + 1) >= 5u;
}

__device__ __forceinline__ uint32_t aread(uint32_t* p) {
  return __hip_atomic_load(p, __ATOMIC_RELAXED, __HIP_MEMORY_SCOPE_AGENT);
}

// find root with guarded path compression: links are only ever LOWERED
// (write r into L[x] only while r < current link), preserving the
// monotone-decreasing invariant => no cycles, guaranteed termination.
__device__ __forceinline__ uint32_t findc(uint32_t* L, uint32_t x) {
  uint32_t r = x, p = aread(&L[r]);
  while (p != r) { r = p; p = aread(&L[r]); }
  while (x > r) {
    uint32_t nx = aread(&L[x]);
    if (nx <= r) break;          // someone already lowered it at least as far
    atomicCAS(&L[x], nx, r);     // best effort, only writes a smaller value
    x = nx;
  }
  return r;
}

// link larger root under smaller => final root == min core CELL of component
__device__ __forceinline__ void unite(uint32_t* L, uint32_t a, uint32_t b) {
  for (;;) {
    a = findc(L, a);
    b = findc(L, b);
    if (a == b) return;
    uint32_t lo = min(a, b), hi = max(a, b);
    if (atomicCAS(&L[hi], hi, lo) == hi) return;  // hi still root => linked
    a = lo; b = hi;
  }
}

// K1 (256x256 = 65536 threads): init lab/cnt/rootbm/ticket (plain stores,
// published by kernel-end writeback) + voxelize points (identical f32 ops).
__global__ __launch_bounds__(256) void k_init_vox(const float* __restrict__ pts,
                                                  uint32_t* __restrict__ ws,
                                                  int npts) {
  int gtid = blockIdx.x * 256 + threadIdx.x;
  uint32_t i4 = (uint32_t)gtid * 4u;
  *reinterpret_cast<uint4*>(&ws[OFF_LAB + i4]) =
      make_uint4(i4, i4 + 1u, i4 + 2u, i4 + 3u);
  *reinterpret_cast<uint4*>(&ws[OFF_CNT + i4]) = make_uint4(0u, 0u, 0u, 0u);
  if (gtid < 2048)
    *reinterpret_cast<uint4*>(&ws[OFF_ROOTBM + gtid * 4]) =
        make_uint4(0u, 0u, 0u, 0u);
  if (gtid == 0) ws[OFF_TICKET] = 0u;
  if (gtid < npts) {
    float x = pts[gtid * 5 + 1];
    float y = pts[gtid * 5 + 2];
    int cx = (int)floorf((x - (-51.2f)) / 0.2f);
    int cy = (int)floorf((y - (-51.2f)) / 0.2f);
    cx = min(max(cx, 0), GRIDW - 1);
    cy = min(max(cy, 0), GRIDW - 1);
    int cell = cy * GRIDW + cx;
    atomicOr(&ws[OFF_OCC + (cell >> 5)], 1u << (cell & 31));
  }
}

// K2 (per-cell): core-core forward unions (E, S, SE, SW), cell-id labels
__global__ __launch_bounds__(256) void k_union(uint32_t* __restrict__ ws) {
  int cell = blockIdx.x * 256 + threadIdx.x;
  const uint32_t* occ = ws + OFF_OCC;
  int x = cell & (GRIDW - 1), y = cell >> 9;
  if (!is_core(occ, x, y)) return;
  uint32_t* lab = ws + OFF_LAB;
  uint32_t c = (uint32_t)cell;
  if (x < GRIDW - 1 && is_core(occ, x + 1, y)) unite(lab, c, c + 1);
  if (y < GRIDW - 1) {
    if (is_core(occ, x, y + 1)) unite(lab, c, c + 512);
    if (x < GRIDW - 1 && is_core(occ, x + 1, y + 1)) unite(lab, c, c + 513);
    if (x > 0 && is_core(occ, x - 1, y + 1)) unite(lab, c, c + 511);
  }
}

// K3 (per-cell): compress (core) + border attach (non-core) + counts;
// last block (ticket) runs finish: dense root numbering, keep filter, max id.
__global__ __launch_bounds__(256) void k_cb(uint32_t* __restrict__ ws,
                                            float* __restrict__ out, int npts) {
  const int tid = threadIdx.x;
  int cell = blockIdx.x * 256 + tid;
  const uint32_t* occ = ws + OFF_OCC;
  uint32_t* lab = ws + OFF_LAB;
  uint32_t* cnt = ws + OFF_CNT;
  __shared__ int slast;
  __shared__ uint32_t wsum[4];
  __shared__ int smax;

  int x = cell & (GRIDW - 1), y = cell >> 9;
  if (occbit(occ, x, y)) {
    uint32_t c = (uint32_t)cell;
    if (is_core(occ, x, y)) {
      uint32_t root = findc(lab, c);
      lab[c] = root;  // same final value as any concurrent compression
      if (root == c) atomicOr(&ws[OFF_ROOTBM + (root >> 5)], 1u << (root & 31));
      atomicAdd(&cnt[root], 1u);
    } else {
      uint32_t m = NONE;
      if (x > 0 && is_core(occ, x - 1, y)) m = min(m, findc(lab, c - 1));
      if (x < GRIDW - 1 && is_core(occ, x + 1, y)) m = min(m, findc(lab, c + 1));
      if (y > 0) {
        if (is_core(occ, x, y - 1)) m = min(m, findc(lab, c - 512));
        if (x < GRIDW - 1 && is_core(occ, x + 1, y - 1)) m = min(m, findc(lab, c - 511));
        if (x > 0 && is_core(occ, x - 1, y - 1)) m = min(m, findc(lab, c - 513));
      }
      if (y < GRIDW - 1) {
        if (is_core(occ, x, y + 1)) m = min(m, findc(lab, c + 512));
        if (x < GRIDW - 1 && is_core(occ, x + 1, y + 1)) m = min(m, findc(lab, c + 513));
        if (x > 0 && is_core(occ, x - 1, y + 1)) m = min(m, findc(lab, c + 511));
      }
      lab[c] = m;  // NONE => noise; borders are never union-find parents
      if (m != NONE) atomicAdd(&cnt[m], 1u);
    }
  }
  // ---- ticket: block atomics are vmcnt-drained by __syncthreads before the
  // ticket add; the last block then reads only atomic-written data.
  __syncthreads();
  if (tid == 0) {
    slast = (atomicAdd(&ws[OFF_TICKET], 1u) == (uint32_t)(NB_CB - 1));
    smax = -1;
  }
  __syncthreads();
  if (!slast) return;
  // ---- finish (256 threads): dense numbering of roots (sorted by cell id),
  // keep = cnt>=20, max kept dense id -> out[npts].
  {
    uint32_t s = 0;
    int base = tid * 32;
    for (int j = 0; j < 32; j++) s += __popc(ws[OFF_ROOTBM + base + j]);
    int lane = tid & 63, wv = tid >> 6;
    uint32_t inc = s;
    for (int d = 1; d < 64; d <<= 1) { uint32_t t = __shfl_up(inc, d); if (lane >= d) inc += t; }
    if (lane == 63) wsum[wv] = inc;
    __syncthreads();
    uint32_t woff = 0;
    for (int k = 0; k < wv; k++) woff += wsum[k];
    int d = (int)(woff + inc - s);
    int mx = -1;
    for (int j = 0; j < 32; j++) {
      int w = base + j;
      uint32_t rb = ws[OFF_ROOTBM + w];
      ws[OFF_RPRE + w] = (uint32_t)d;
      uint32_t keep = 0;
      while (rb) {
        int b = __ffs(rb) - 1; rb &= rb - 1;
        uint32_t rr = (uint32_t)w * 32u + (uint32_t)b;
        if (cnt[rr] >= 20u) { keep |= 1u << b; mx = d; }
        d++;
      }
      ws[OFF_KEEP + w] = keep;
    }
    if (mx >= 0) atomicMax(&smax, mx);
    __syncthreads();
    if (tid == 0) out[npts] = (float)(smax + 1);
  }
}

// K4: scatter dense labels back to points (pure lookups, no rank math)
__global__ __launch_bounds__(256) void k_scatter(const float* __restrict__ pts,
                                                 const uint32_t* __restrict__ ws,
                                                 float* __restrict__ out,
                                                 int npts) {
  int i = blockIdx.x * 256 + threadIdx.x;
  if (i >= npts) return;
  float x = pts[i * 5 + 1];
  float y = pts[i * 5 + 2];
  int cx = (int)floorf((x - (-51.2f)) / 0.2f);  // identical math to k_init_vox
  int cy = (int)floorf((y - (-51.2f)) / 0.2f);
  cx = min(max(cx, 0), GRIDW - 1);
  cy = min(max(cy, 0), GRIDW - 1);
  uint32_t cell = (uint32_t)(cy * GRIDW + cx);
  uint32_t l = ws[OFF_LAB + cell];
  float o = -1.0f;
  if (l != NONE && ((ws[OFF_KEEP + (l >> 5)] >> (l & 31)) & 1)) {
    int dnum = (int)ws[OFF_RPRE + (l >> 5)] +
               __popc(ws[OFF_ROOTBM + (l >> 5)] & ((1u << (l & 31)) - 1u));
    o = (float)dnum;
  }
  out[i] = o;
}

extern "C" void kernel_launch(void* const* d_in, const int* in_sizes, int n_in,
                              void* d_out, int out_size, void* d_ws, size_t ws_size,
                              hipStream_t stream) {
  const float* pts = (const float*)d_in[0];
  int npts = in_sizes[0] / 5;  // points are (N,5) float32
  uint32_t* ws = (uint32_t*)d_ws;
  float* out = (float*)d_out;
  int pblocks = (npts + 255) / 256;
  hipMemsetAsync(d_ws, 0, NWORDS * 4, stream);  // occ only (32 KB)
  k_init_vox<<<256, 256, 0, stream>>>(pts, ws, npts);
  k_union<<<NCELLS / 256, 256, 0, stream>>>(ws);
  k_cb<<<NB_CB, 256, 0, stream>>>(ws, out, npts);
  k_scatter<<<pblocks, 256, 0, stream>>>(pts, ws, out, npts);
}

// Round 7
// 116.819 us; speedup vs baseline: 1.9239x; 1.0579x over previous
//
#include <hip/hip_runtime.h>
#include <stdint.h>

// DBSCAN-on-voxel-grid, exact port of the JAX reference for batch_size==1.
// Grid 512x512, eps=1.5 => 8-connected adjacency, min_samples=5 (voxels,
// incl. self), clusters with <20 voxels dropped.
//
// R13: R12's counters isolated the bottleneck: union/attach phases cost
// 43-66us because every union-find hop is an agent-scope atomic at the
// memory-side coherence point (~900cyc), serialized 9-deep per occupied
// cell. Fix: rank-compress (<=8192 voxels) so lab fits in 32KB LDS and run
// ALL graph work in ONE 1024-thread block with ~40cyc LDS hops (R10 proved
// the LDS guarded union-find correct; R10's mistake was putting the
// memory-parallel phases on one CU too). Wide kernels keep doing the
// memory-parallel work (voxelize, scatter).
// 4 dispatches: memset(occ+cnt 64KB), k_vox (wide), k_union1 (1 block:
// occ->LDS, core masks, rank scan, LDS unions, LDS border-attach, counts,
// finish, per-voxel dense label -> global labf), k_scatter (pure gather).

#define GRIDW 512
#define WPR 16        // bitmap words per row
#define NWORDS 8192   // 512*512/32
#define NONE 0xFFFFFFFFu
#define BS 1024

// ---- global ws layout (uint32 units) ----
#define OFF_OCC  0       // 8192: occupancy bitmap (memset)
#define OFF_CNT  8192    // 8192: per-root-RANK voxel counts (memset)
#define OFF_LABF 16384   // 262144: final dense label per cell (NONE = noise)
#define MEMSET_BYTES (16384 * 4)

// per-position horizontal (west+self+east) 2-bit counts for a row of 32 cells
__device__ __forceinline__ void hsum(uint32_t l, uint32_t c, uint32_t r,
                                     uint32_t& h0, uint32_t& h1) {
  uint32_t Wb = (c << 1) | (l >> 31);
  uint32_t Eb = (c >> 1) | (r << 31);
  h0 = Wb ^ c ^ Eb;
  h1 = (Wb & c) | (Eb & (Wb ^ c));
}

// per-position (sum of three 2-bit row counts) >= 5 (bit-sliced adders)
__device__ __forceinline__ uint32_t ge5(uint32_t a0, uint32_t a1, uint32_t b0,
                                        uint32_t b1, uint32_t c0, uint32_t c1) {
  uint32_t u0 = a0 ^ b0, cy = a0 & b0;
  uint32_t t = a1 ^ b1;
  uint32_t u1 = t ^ cy;
  uint32_t u2 = (a1 & b1) | (cy & t);
  uint32_t v0 = u0 ^ c0, k0 = u0 & c0;
  uint32_t t2 = u1 ^ c1;
  uint32_t v1 = t2 ^ k0;
  uint32_t k1 = (u1 & c1) | (k0 & t2);
  uint32_t v2 = u2 ^ k1;
  uint32_t v3 = u2 & k1;
  return v3 | (v2 & (v1 | v0));  // count in {5..9}
}

// LDS union-find (R10-proven). Links only ever LOWERED => monotone =>
// no cycles, guaranteed termination. ~40cyc hops vs ~900cyc global.
__device__ __forceinline__ uint32_t lread(uint32_t* L, uint32_t i) {
  return __hip_atomic_load(&L[i], __ATOMIC_RELAXED, __HIP_MEMORY_SCOPE_WORKGROUP);
}

__device__ __forceinline__ uint32_t findc(uint32_t* L, uint32_t x) {
  uint32_t r = x, p = lread(L, r);
  while (p != r) { r = p; p = lread(L, r); }
  while (x > r) {
    uint32_t nx = lread(L, x);
    if (nx <= r) break;          // someone already lowered it at least as far
    atomicCAS(&L[x], nx, r);     // best effort, only writes a smaller value
    x = nx;
  }
  return r;
}

__device__ __forceinline__ void unite(uint32_t* L, uint32_t a, uint32_t b) {
  for (;;) {
    a = findc(L, a);
    b = findc(L, b);
    if (a == b) return;
    uint32_t lo = min(a, b), hi = max(a, b);
    if (atomicCAS(&L[hi], hi, lo) == hi) return;  // hi still root => linked
    a = lo; b = hi;
  }
}

// K1 (wide): voxelize points -> occupancy bits (identical f32 ops to jnp)
__global__ __launch_bounds__(256) void k_vox(const float* __restrict__ pts,
                                             uint32_t* __restrict__ ws,
                                             int npts) {
  int i = blockIdx.x * 256 + threadIdx.x;
  if (i >= npts) return;
  float x = pts[i * 5 + 1];
  float y = pts[i * 5 + 2];
  int cx = (int)floorf((x - (-51.2f)) / 0.2f);
  int cy = (int)floorf((y - (-51.2f)) / 0.2f);
  cx = min(max(cx, 0), GRIDW - 1);
  cy = min(max(cy, 0), GRIDW - 1);
  int cell = cy * GRIDW + cx;
  atomicOr(&ws[OFF_OCC + (cell >> 5)], 1u << (cell & 31));
}

// K2 (ONE block, 1024 threads): the entire clustering graph in LDS.
__global__ __launch_bounds__(BS, 1) void k_union1(uint32_t* __restrict__ ws,
                                                  float* __restrict__ out,
                                                  int npts) {
  __shared__ uint32_t s_occ[NWORDS];    // 32KB
  __shared__ uint32_t s_cm[NWORDS];     // 32KB core mask
  __shared__ uint16_t s_pre[NWORDS];    // 16KB exclusive voxel-rank prefix
  __shared__ uint32_t s_cell[NWORDS];   // 32KB rank -> cell id
  __shared__ uint32_t s_lab[NWORDS];    // 32KB union-find by rank
  __shared__ uint32_t s_rootbm[256];    // root bitmap by rank
  __shared__ uint32_t s_keep[256];
  __shared__ uint32_t s_rpre[256];
  __shared__ uint32_t wsum[16];
  __shared__ uint32_t s_nv;
  __shared__ int smax;
  const int tid = threadIdx.x;

  // ---- P0: occ global -> LDS (uint4), zero rootbm ----
  {
    const uint4* g = reinterpret_cast<const uint4*>(ws + OFF_OCC);
    uint4 v0 = g[tid];
    uint4 v1 = g[tid + BS];
    reinterpret_cast<uint4*>(s_occ)[tid] = v0;
    reinterpret_cast<uint4*>(s_occ)[tid + BS] = v1;
  }
  if (tid < 256) s_rootbm[tid] = 0u;
  if (tid == 0) smax = -1;
  __syncthreads();

  // ---- P1: per-word (8 contiguous/thread): core mask + popc scan +
  //          rank tables (pre/cell) + union-find init ----
  const int base = tid * 8;
  uint32_t s = 0;
  for (int j = 0; j < 8; j++) {
    int wi = base + j;
    uint32_t cB = s_occ[wi];
    s += __popc(cB);
    int y = wi >> 4, wx = wi & 15;
    uint32_t lB = wx ? s_occ[wi - 1] : 0u;
    uint32_t rB = (wx < 15) ? s_occ[wi + 1] : 0u;
    uint32_t cA = 0, lA = 0, rA = 0, cC = 0, lC = 0, rC = 0;
    if (y > 0) { int wa = wi - WPR; cA = s_occ[wa]; lA = wx ? s_occ[wa - 1] : 0u; rA = (wx < 15) ? s_occ[wa + 1] : 0u; }
    if (y < GRIDW - 1) { int wc = wi + WPR; cC = s_occ[wc]; lC = wx ? s_occ[wc - 1] : 0u; rC = (wx < 15) ? s_occ[wc + 1] : 0u; }
    uint32_t a0, a1, b0, b1, c0, c1;
    hsum(lA, cA, rA, a0, a1); hsum(lB, cB, rB, b0, b1); hsum(lC, cC, rC, c0, c1);
    s_cm[wi] = ge5(a0, a1, b0, b1, c0, c1) & cB;
  }
  {
    int lane = tid & 63, wv = tid >> 6;
    uint32_t inc = s;
    for (int d = 1; d < 64; d <<= 1) { uint32_t t = __shfl_up(inc, d); if (lane >= d) inc += t; }
    if (lane == 63) wsum[wv] = inc;
    __syncthreads();
    uint32_t woff = 0;
    for (int k = 0; k < wv; k++) woff += wsum[k];
    uint32_t excl = woff + inc - s;
    if (tid == BS - 1) s_nv = excl + s;
    for (int j = 0; j < 8; j++) {
      int wi = base + j;
      uint32_t bits = s_occ[wi];
      s_pre[wi] = (uint16_t)excl;
      while (bits) {
        int b = __ffs(bits) - 1; bits &= bits - 1;
        s_cell[excl] = (uint32_t)(wi * 32 + b);
        s_lab[excl] = excl;
        excl++;
      }
    }
  }
  __syncthreads();

  // ---- P2: per-RANK (strided, load-balanced) core-core forward unions ----
  const uint32_t nv = s_nv;
  for (uint32_t r = tid; r < nv; r += BS) {
    uint32_t cell = s_cell[r];
    int w = (int)(cell >> 5), b = (int)(cell & 31);
    uint32_t cw = s_cm[w];
    if (!((cw >> b) & 1)) continue;
    int y = w >> 4, wx = w & 15;
    bool eC = (b < 31) ? ((cw >> (b + 1)) & 1) : ((wx < 15) ? (s_cm[w + 1] & 1) : false);
    if (eC) unite(s_lab, r, (b < 31) ? r + 1 : (uint32_t)s_pre[w + 1]);
    if (y < GRIDW - 1) {
      uint32_t cmS = s_cm[w + WPR], occS = s_occ[w + WPR];
      uint32_t rS = s_pre[w + WPR];
      if ((cmS >> b) & 1) unite(s_lab, r, rS + __popc(occS & ((1u << b) - 1u)));
      bool seC = (b < 31) ? ((cmS >> (b + 1)) & 1) : ((wx < 15) ? (s_cm[w + WPR + 1] & 1) : false);
      if (seC) unite(s_lab, r, (b < 31) ? rS + __popc(occS & ((2u << b) - 1u)) : (uint32_t)s_pre[w + WPR + 1]);
      bool swC = (b > 0) ? ((cmS >> (b - 1)) & 1) : ((wx > 0) ? (s_cm[w + WPR - 1] >> 31) : false);
      if (swC) unite(s_lab, r, (b > 0) ? rS + __popc(occS & ((1u << (b - 1)) - 1u)) : rS - 1);
    }
  }
  __syncthreads();

  // ---- P3: per-RANK compress (core) + border attach + counts (global
  //          fire-and-forget atomics; reads happen after the barrier) ----
  uint32_t* cnt = ws + OFF_CNT;
  for (uint32_t r = tid; r < nv; r += BS) {
    uint32_t cell = s_cell[r];
    int w = (int)(cell >> 5), b = (int)(cell & 31);
    uint32_t cw = s_cm[w];
    int y = w >> 4, wx = w & 15;
    if ((cw >> b) & 1) {
      uint32_t root = findc(s_lab, r);
      s_lab[r] = root;
      if (root == r) atomicOr(&s_rootbm[r >> 5], 1u << (r & 31));
      atomicAdd(&cnt[root], 1u);
    } else {
      uint32_t m = NONE;
      bool wC = (b > 0) ? ((cw >> (b - 1)) & 1) : ((wx > 0) ? (s_cm[w - 1] >> 31) : false);
      if (wC) m = min(m, findc(s_lab, (b > 0) ? r - 1 : (uint32_t)s_pre[w] - 1u));
      bool eC = (b < 31) ? ((cw >> (b + 1)) & 1) : ((wx < 15) ? (s_cm[w + 1] & 1) : false);
      if (eC) m = min(m, findc(s_lab, (b < 31) ? r + 1 : (uint32_t)s_pre[w + 1]));
      if (y > 0) {
        uint32_t cmN = s_cm[w - WPR], occN = s_occ[w - WPR];
        uint32_t rN = s_pre[w - WPR];
        if ((cmN >> b) & 1) m = min(m, findc(s_lab, rN + __popc(occN & ((1u << b) - 1u))));
        bool neC = (b < 31) ? ((cmN >> (b + 1)) & 1) : ((wx < 15) ? (s_cm[w - WPR + 1] & 1) : false);
        if (neC) m = min(m, findc(s_lab, (b < 31) ? rN + __popc(occN & ((2u << b) - 1u)) : (uint32_t)s_pre[w - WPR + 1]));
        bool nwC = (b > 0) ? ((cmN >> (b - 1)) & 1) : ((wx > 0) ? (s_cm[w - WPR - 1] >> 31) : false);
        if (nwC) m = min(m, findc(s_lab, (b > 0) ? rN + __popc(occN & ((1u << (b - 1)) - 1u)) : rN - 1u));
      }
      if (y < GRIDW - 1) {
        uint32_t cmS = s_cm[w + WPR], occS = s_occ[w + WPR];
        uint32_t rS = s_pre[w + WPR];
        if ((cmS >> b) & 1) m = min(m, findc(s_lab, rS + __popc(occS & ((1u << b) - 1u))));
        bool seC = (b < 31) ? ((cmS >> (b + 1)) & 1) : ((wx < 15) ? (s_cm[w + WPR + 1] & 1) : false);
        if (seC) m = min(m, findc(s_lab, (b < 31) ? rS + __popc(occS & ((2u << b) - 1u)) : (uint32_t)s_pre[w + WPR + 1]));
        bool swC = (b > 0) ? ((cmS >> (b - 1)) & 1) : ((wx > 0) ? (s_cm[w + WPR - 1] >> 31) : false);
        if (swC) m = min(m, findc(s_lab, (b > 0) ? rS + __popc(occS & ((1u << (b - 1)) - 1u)) : rS - 1u));
      }
      s_lab[r] = m;  // NONE => noise; border ranks are never union-find parents
      if (m != NONE) atomicAdd(&cnt[m], 1u);
    }
  }
  __syncthreads();  // drains this block's cnt atomics (vmcnt) + joins waves

  // ---- P4: finish (tid<256, one rootbm word each): dense root numbering
  //          (sorted by rank = by cell id), keep = cnt>=20, max kept id ----
  {
    int lane = tid & 63, wv = tid >> 6;
    if (tid < 256) {
      uint32_t v = __popc(s_rootbm[tid]);
      uint32_t inc = v;
      for (int d = 1; d < 64; d <<= 1) { uint32_t t = __shfl_up(inc, d); if (lane >= d) inc += t; }
      s_rpre[tid] = inc;  // temp: inclusive within-wave
      if (lane == 63) wsum[wv] = inc;
    }
    __syncthreads();
    if (tid < 256) {
      uint32_t v = __popc(s_rootbm[tid]);
      uint32_t inc = s_rpre[tid];
      uint32_t woff = 0;
      for (int k = 0; k < wv; k++) woff += wsum[k];
      uint32_t excl = woff + inc - v;
      s_rpre[tid] = excl;
      uint32_t rb = s_rootbm[tid];
      uint32_t keep = 0;
      int mx = -1, d = (int)excl;
      while (rb) {
        int b = __ffs(rb) - 1; rb &= rb - 1;
        uint32_t rr = (uint32_t)tid * 32u + (uint32_t)b;
        if (cnt[rr] >= 20u) { keep |= 1u << b; mx = d; }
        d++;
      }
      s_keep[tid] = keep;
      if (mx >= 0) atomicMax(&smax, mx);
    }
  }
  __syncthreads();

  // ---- P5: per-RANK final dense label -> global labf[cell]; out[npts] ----
  for (uint32_t r = tid; r < nv; r += BS) {
    uint32_t l = s_lab[r];
    uint32_t o = NONE;
    if (l != NONE && ((s_keep[l >> 5] >> (l & 31)) & 1))
      o = s_rpre[l >> 5] + __popc(s_rootbm[l >> 5] & ((1u << (l & 31)) - 1u));
    ws[OFF_LABF + s_cell[r]] = o;
  }
  if (tid == 0) out[npts] = (float)(smax + 1);
}

// K3 (wide): pure gather of per-cell dense labels
__global__ __launch_bounds__(256) void k_scatter(const float* __restrict__ pts,
                                                 const uint32_t* __restrict__ ws,
                                                 float* __restrict__ out,
                                                 int npts) {
  int i = blockIdx.x * 256 + threadIdx.x;
  if (i >= npts) return;
  float x = pts[i * 5 + 1];
  float y = pts[i * 5 + 2];
  int cx = (int)floorf((x - (-51.2f)) / 0.2f);  // identical math to k_vox
  int cy = (int)floorf((y - (-51.2f)) / 0.2f);
  cx = min(max(cx, 0), GRIDW - 1);
  cy = min(max(cy, 0), GRIDW - 1);
  uint32_t cell = (uint32_t)(cy * GRIDW + cx);
  uint32_t l = ws[OFF_LABF + cell];
  out[i] = (l == NONE) ? -1.0f : (float)l;
}

extern "C" void kernel_launch(void* const* d_in, const int* in_sizes, int n_in,
                              void* d_out, int out_size, void* d_ws, size_t ws_size,
                              hipStream_t stream) {
  const float* pts = (const float*)d_in[0];
  int npts = in_sizes[0] / 5;  // points are (N,5) float32
  uint32_t* ws = (uint32_t*)d_ws;
  float* out = (float*)d_out;
  int pblocks = (npts + 255) / 256;
  hipMemsetAsync(d_ws, 0, MEMSET_BYTES, stream);  // occ + cnt (64KB)
  k_vox<<<pblocks, 256, 0, stream>>>(pts, ws, npts);
  k_union1<<<1, BS, 0, stream>>>(ws, out, npts);
  k_scatter<<<pblocks, 256, 0, stream>>>(pts, ws, out, npts);
}